// Round 3
// baseline (516.370 us; speedup 1.0000x reference)
//
#include <hip/hip_runtime.h>
#include <cstddef>

// Multigrid F-cycle advection, 4096^2 f32, T=4 outer iterations.
// R3: mega-fused tail kernel k_fused per iteration:
//   E1 = up(E2, r1)            (in-LDS, recomputed with halo redundancy)
//   w  = v - prolong(E1)       (in-LDS)
//   v' = w - smooth(bc(w))     (in-LDS + global store)
//   r1' = restrict(smooth(bc(v')))   (next iteration's residual)
// This removes the E1 global round-trip (33.6 MB/iter) and the v' re-read
// by the next smooth_restrict (67 MB/iter), plus 2 launches/iter.
// All FP op orders identical to the R2 (passing) kernel -> bitwise-same output.

constexpr float CW = 0.05f;  // CXW == CYW == DT/DX/2

// e_new = (Pc - smooth_zero_pad(P)) + r, reference rounding order.
__device__ __forceinline__ float up_val(float Pc, float Pu, float Pd, float Pl,
                                        float Pr, float rv) {
  float sm = CW * Pu - CW * Pd + CW * Pl + Pc - CW * Pr;
  return (Pc - sm) + rv;
}

// ---------------------------------------------------------------------------
// r1 = restrict(smooth(bc(v))): v 4096^2 -> r1 2048^2.  (iteration 0 only)
__global__ __launch_bounds__(256) void k_smooth_restrict(
    const float* __restrict__ v, float* __restrict__ r1) {
  const int n = 4096, h = 2048;
  int bj = blockIdx.x * blockDim.x + threadIdx.x;
  int bi = blockIdx.y * blockDim.y + threadIdx.y;
  int c0 = 4 * bj;
  int cl = max(c0 - 1, 0), cr = min(c0 + 4, n - 1);
  float a[6][6];
#pragma unroll
  for (int rr = 0; rr < 6; ++rr) {
    int R = min(max(4 * bi - 1 + rr, 0), n - 1);
    const float* row = v + (size_t)R * n;
    float4 m = *reinterpret_cast<const float4*>(row + c0);
    a[rr][0] = row[cl];
    a[rr][1] = m.x; a[rr][2] = m.y; a[rr][3] = m.z; a[rr][4] = m.w;
    a[rr][5] = row[cr];
  }
#pragma unroll
  for (int oi = 0; oi < 2; ++oi) {
    float2 o;
#pragma unroll
    for (int oj = 0; oj < 2; ++oj) {
      float s[2][2];
#pragma unroll
      for (int p = 0; p < 2; ++p)
#pragma unroll
        for (int q = 0; q < 2; ++q) {
          int P = 2 * oi + p, Q = 2 * oj + q;
          s[p][q] = CW * a[P][Q + 1] - CW * a[P + 2][Q + 1]
                  + CW * a[P + 1][Q] + a[P + 1][Q + 1] - CW * a[P + 1][Q + 2];
        }
      float val = 0.25f * (((s[0][0] + s[1][0]) + s[0][1]) + s[1][1]);
      (oj ? o.y : o.x) = val;
    }
    *reinterpret_cast<float2*>(r1 + (size_t)(2 * bi + oi) * h + 2 * bj) = o;
  }
}

// ---------------------------------------------------------------------------
// y = restrict(x) (n -> n/2), z = restrict(y) (n/2 -> n/4).
__global__ __launch_bounds__(256) void k_restrict2(
    const float* __restrict__ x, float* __restrict__ y,
    float* __restrict__ z, int n) {
  int h = n >> 1, q = n >> 2;
  int j = blockIdx.x * blockDim.x + threadIdx.x;
  int i = blockIdx.y * blockDim.y + threadIdx.y;
  if (i >= q || 2 * j >= q) return;
  float xr[4][8];
#pragma unroll
  for (int rr = 0; rr < 4; ++rr) {
    const float* row = x + (size_t)(4 * i + rr) * n + 8 * j;
    float4 m0 = reinterpret_cast<const float4*>(row)[0];
    float4 m1 = reinterpret_cast<const float4*>(row)[1];
    xr[rr][0] = m0.x; xr[rr][1] = m0.y; xr[rr][2] = m0.z; xr[rr][3] = m0.w;
    xr[rr][4] = m1.x; xr[rr][5] = m1.y; xr[rr][6] = m1.z; xr[rr][7] = m1.w;
  }
  float yv[2][4];
#pragma unroll
  for (int a = 0; a < 2; ++a)
#pragma unroll
    for (int b = 0; b < 4; ++b)
      yv[a][b] = 0.25f * (((xr[2 * a][2 * b] + xr[2 * a + 1][2 * b])
                           + xr[2 * a][2 * b + 1]) + xr[2 * a + 1][2 * b + 1]);
#pragma unroll
  for (int a = 0; a < 2; ++a) {
    float4 o; o.x = yv[a][0]; o.y = yv[a][1]; o.z = yv[a][2]; o.w = yv[a][3];
    *reinterpret_cast<float4*>(y + (size_t)(2 * i + a) * h + 4 * j) = o;
  }
  float2 zo;
  zo.x = 0.25f * (((yv[0][0] + yv[1][0]) + yv[0][1]) + yv[1][1]);
  zo.y = 0.25f * (((yv[0][2] + yv[1][2]) + yv[0][3]) + yv[1][3]);
  *reinterpret_cast<float2*>(z + (size_t)i * q + 2 * j) = zo;
}

// ---------------------------------------------------------------------------
// Coarse-grid correction for levels 256..1024.
__global__ __launch_bounds__(256) void k_up(
    const float* __restrict__ Ep, const float* __restrict__ r,
    float* __restrict__ Eo, int n) {
  int s = n >> 1;
  int j = blockIdx.x * blockDim.x + threadIdx.x;
  int i = blockIdx.y * blockDim.y + threadIdx.y;
  if (i >= s || j >= (n >> 2)) return;
  const float* ec = Ep + (size_t)i * s + 2 * j;
  float epc0 = ec[0], epc1 = ec[1];
  float epl = (j > 0) ? ec[-1] : 0.0f;
  float epr = (2 * j + 2 < s) ? ec[2] : 0.0f;
  float epu0 = 0.0f, epu1 = 0.0f, epd0 = 0.0f, epd1 = 0.0f;
  if (i > 0)     { epu0 = ec[-s]; epu1 = ec[-s + 1]; }
  if (i < s - 1) { epd0 = ec[s];  epd1 = ec[s + 1]; }
  {
    float4 rv = *reinterpret_cast<const float4*>(r + (size_t)(2 * i) * n + 4 * j);
    float4 o;
    o.x = up_val(epc0, epu0, epc0, epl,  epc0, rv.x);
    o.y = up_val(epc0, epu0, epc0, epc0, epc1, rv.y);
    o.z = up_val(epc1, epu1, epc1, epc0, epc1, rv.z);
    o.w = up_val(epc1, epu1, epc1, epc1, epr,  rv.w);
    *reinterpret_cast<float4*>(Eo + (size_t)(2 * i) * n + 4 * j) = o;
  }
  {
    float4 rv = *reinterpret_cast<const float4*>(r + (size_t)(2 * i + 1) * n + 4 * j);
    float4 o;
    o.x = up_val(epc0, epc0, epd0, epl,  epc0, rv.x);
    o.y = up_val(epc0, epc0, epd0, epc0, epc1, rv.y);
    o.z = up_val(epc1, epc1, epd1, epc0, epc1, rv.z);
    o.w = up_val(epc1, epc1, epd1, epc1, epr,  rv.w);
    *reinterpret_cast<float4*>(Eo + (size_t)(2 * i + 1) * n + 4 * j) = o;
  }
}

// ---------------------------------------------------------------------------
// Single-block kernel: r5 (128^2) -> r6..r9 (LDS), then up-sweep E8..E6 -> E5.
__global__ void k_coarse(const float* __restrict__ r5, float* __restrict__ E5) {
  __shared__ float r6[64 * 64];
  __shared__ float r7[32 * 32];
  __shared__ float r8[16 * 16];
  __shared__ float r9[8 * 8];
  __shared__ float E8[16 * 16];
  __shared__ float E7[32 * 32];
  __shared__ float E6[64 * 64];
  int tid = threadIdx.x, nt = blockDim.x;

  auto up_lds = [&](const float* Ep, const float* rr, int i, int c, int nn) {
    int ss = nn >> 1;
    float Pc = Ep[(i >> 1) * ss + (c >> 1)];
    float Pu = (i > 0)      ? Ep[((i - 1) >> 1) * ss + (c >> 1)] : 0.0f;
    float Pd = (i < nn - 1) ? Ep[((i + 1) >> 1) * ss + (c >> 1)] : 0.0f;
    float Pl = (c > 0)      ? Ep[(i >> 1) * ss + ((c - 1) >> 1)] : 0.0f;
    float Pr = (c < nn - 1) ? Ep[(i >> 1) * ss + ((c + 1) >> 1)] : 0.0f;
    return up_val(Pc, Pu, Pd, Pl, Pr, rr[i * nn + c]);
  };

  for (int idx = tid; idx < 64 * 64; idx += nt) {
    int I = idx >> 6, J = idx & 63;
    float a = r5[(2 * I) * 128 + 2 * J],     b = r5[(2 * I + 1) * 128 + 2 * J];
    float c = r5[(2 * I) * 128 + 2 * J + 1], d = r5[(2 * I + 1) * 128 + 2 * J + 1];
    r6[idx] = 0.25f * (((a + b) + c) + d);
  }
  __syncthreads();
  for (int idx = tid; idx < 32 * 32; idx += nt) {
    int I = idx >> 5, J = idx & 31;
    float a = r6[(2 * I) * 64 + 2 * J],     b = r6[(2 * I + 1) * 64 + 2 * J];
    float c = r6[(2 * I) * 64 + 2 * J + 1], d = r6[(2 * I + 1) * 64 + 2 * J + 1];
    r7[idx] = 0.25f * (((a + b) + c) + d);
  }
  __syncthreads();
  for (int idx = tid; idx < 16 * 16; idx += nt) {
    int I = idx >> 4, J = idx & 15;
    float a = r7[(2 * I) * 32 + 2 * J],     b = r7[(2 * I + 1) * 32 + 2 * J];
    float c = r7[(2 * I) * 32 + 2 * J + 1], d = r7[(2 * I + 1) * 32 + 2 * J + 1];
    r8[idx] = 0.25f * (((a + b) + c) + d);
  }
  __syncthreads();
  for (int idx = tid; idx < 8 * 8; idx += nt) {
    int I = idx >> 3, J = idx & 7;
    float a = r8[(2 * I) * 16 + 2 * J],     b = r8[(2 * I + 1) * 16 + 2 * J];
    float c = r8[(2 * I) * 16 + 2 * J + 1], d = r8[(2 * I + 1) * 16 + 2 * J + 1];
    r9[idx] = 0.25f * (((a + b) + c) + d);
  }
  __syncthreads();
  for (int idx = tid; idx < 16 * 16; idx += nt)
    E8[idx] = up_lds(r9, r8, idx >> 4, idx & 15, 16);
  __syncthreads();
  for (int idx = tid; idx < 32 * 32; idx += nt)
    E7[idx] = up_lds(E8, r7, idx >> 5, idx & 31, 32);
  __syncthreads();
  for (int idx = tid; idx < 64 * 64; idx += nt)
    E6[idx] = up_lds(E7, r6, idx >> 6, idx & 63, 64);
  __syncthreads();
  for (int idx = tid; idx < 128 * 128; idx += nt)
    E5[idx] = up_lds(E6, r5, idx >> 7, idx & 127, 128);
}

// ---------------------------------------------------------------------------
// Fused tail: E1(LDS) <- up(E2, r1); w(LDS) <- v - P(E1); v'(LDS+global);
// r1'(global) <- restrict(smooth(bc(v')))   [skipped on last iteration].
// Block tile: 16 rows x 256 cols of v'. Halo rims computed redundantly.
template <bool WRITE_R1>
__global__ __launch_bounds__(256) void k_fused(
    const float* __restrict__ v, const float* __restrict__ E2,
    const float* __restrict__ r1, float* __restrict__ vout,
    float* __restrict__ r1o) {
  const int n = 4096, h = 2048, s2 = 1024;
  const int BI = 16, BJ = 256;
  __shared__ float e1s[10][132];   // E1 rows y0/2-1 .. y0/2+8, cols x0/2-1 .. x0/2+128
  __shared__ float wsh[20][264];   // w  rows y0-2 .. y0+17, cols x0-2 .. x0+257
  __shared__ float vps[18][264];   // v' rows y0-1 .. y0+16, cols x0-1 .. x0+256
  int tid = threadIdx.x;
  int x0 = blockIdx.x * BJ;
  int y0 = blockIdx.y * BI;
  int eb_r = (y0 >> 1) - 1;        // global E1 row of e1s[0][*] (pre-clamp)
  int eb_c = (x0 >> 1) - 1;

  // Stage A: E1 region (10 x 130) = up(E2, r1); clamped-global, op order == k_up.
  for (int idx = tid; idx < 10 * 130; idx += 256) {
    int er = idx / 130, ec = idx % 130;
    int gi = min(max(eb_r + er, 0), h - 1);
    int gc = min(max(eb_c + ec, 0), h - 1);
    float Pc = E2[(size_t)(gi >> 1) * s2 + (gc >> 1)];
    float Pu = (gi > 0)     ? E2[(size_t)((gi - 1) >> 1) * s2 + (gc >> 1)] : 0.0f;
    float Pd = (gi < h - 1) ? E2[(size_t)((gi + 1) >> 1) * s2 + (gc >> 1)] : 0.0f;
    float Pl = (gc > 0)     ? E2[(size_t)(gi >> 1) * s2 + ((gc - 1) >> 1)] : 0.0f;
    float Pr = (gc < h - 1) ? E2[(size_t)(gi >> 1) * s2 + ((gc + 1) >> 1)] : 0.0f;
    e1s[er][ec] = up_val(Pc, Pu, Pd, Pl, Pr, r1[(size_t)gi * h + gc]);
  }
  __syncthreads();

  // Stage B: w = v - prolong(E1), region 20 x 260. Interior via float4.
  for (int idx = tid; idx < 20 * 64; idx += 256) {
    int wr = idx >> 6, f = idx & 63;
    int Rc = min(max(y0 - 2 + wr, 0), n - 1);
    int er = (Rc >> 1) - eb_r;
    float4 m = *reinterpret_cast<const float4*>(v + (size_t)Rc * n + x0 + 4 * f);
    float e0 = e1s[er][2 * f + 1], e1v = e1s[er][2 * f + 2];
    wsh[wr][2 + 4 * f]     = m.x - e0;
    wsh[wr][2 + 4 * f + 1] = m.y - e0;
    wsh[wr][2 + 4 * f + 2] = m.z - e1v;
    wsh[wr][2 + 4 * f + 3] = m.w - e1v;
  }
  for (int idx = tid; idx < 20 * 4; idx += 256) {   // edge cols 0,1,258,259
    int wr = idx >> 2, k = idx & 3;
    int wc = (k < 2) ? k : 256 + k;
    int Rc = min(max(y0 - 2 + wr, 0), n - 1);
    int Cc = min(max(x0 - 2 + wc, 0), n - 1);
    int er = (Rc >> 1) - eb_r;
    int ec = (Cc >> 1) - eb_c;
    wsh[wr][wc] = v[(size_t)Rc * n + Cc] - e1s[er][ec];
  }
  __syncthreads();

  // Stage C: v' = w - smooth(bc(w)), region 18 x 258. Op order == k_final.
  for (int idx = tid; idx < 18 * 258; idx += 256) {
    int pr = idx / 258, pc = idx % 258;
    float wc = wsh[pr + 1][pc + 1];
    float sm = CW * wsh[pr][pc + 1] - CW * wsh[pr + 2][pc + 1]
             + CW * wsh[pr + 1][pc] + wc - CW * wsh[pr + 1][pc + 2];
    vps[pr][pc] = wc - sm;
  }
  __syncthreads();

  // Write v' interior (16 x 256) as float4.
  for (int idx = tid; idx < 16 * 64; idx += 256) {
    int rr = idx >> 6, f = idx & 63;
    float4 o;
    o.x = vps[rr + 1][4 * f + 1];
    o.y = vps[rr + 1][4 * f + 2];
    o.z = vps[rr + 1][4 * f + 3];
    o.w = vps[rr + 1][4 * f + 4];
    *reinterpret_cast<float4*>(vout + (size_t)(y0 + rr) * n + x0 + 4 * f) = o;
  }

  if constexpr (WRITE_R1) {
    // Stage D: r1' (8 x 128) = restrict(smooth(bc(v'))). Op order == SR.
    for (int idx = tid; idx < 8 * 128; idx += 256) {
      int a = idx >> 7, b = idx & 127;
      int gi = (y0 >> 1) + a, gj = (x0 >> 1) + b;
      float sacc[2][2];
#pragma unroll
      for (int p = 0; p < 2; ++p)
#pragma unroll
        for (int q = 0; q < 2; ++q) {
          int R = 2 * gi + p, C = 2 * gj + q;
          int Ru = max(R - 1, 0), Rd = min(R + 1, n - 1);
          int Cl = max(C - 1, 0), Cr = min(C + 1, n - 1);
          float ce = vps[R - y0 + 1][C - x0 + 1];
          sacc[p][q] = CW * vps[Ru - y0 + 1][C - x0 + 1]
                     - CW * vps[Rd - y0 + 1][C - x0 + 1]
                     + CW * vps[R - y0 + 1][Cl - x0 + 1]
                     + ce
                     - CW * vps[R - y0 + 1][Cr - x0 + 1];
        }
      r1o[(size_t)gi * h + gj] =
          0.25f * (((sacc[0][0] + sacc[1][0]) + sacc[0][1]) + sacc[1][1]);
    }
  }
}

// ---------------------------------------------------------------------------
extern "C" void kernel_launch(void* const* d_in, const int* in_sizes, int n_in,
                              void* d_out, int out_size, void* d_ws, size_t ws_size,
                              hipStream_t stream) {
  (void)in_sizes; (void)n_in; (void)out_size;
  float* u = (float*)d_in[0];
  float* out = (float*)d_out;
  char* ws = (char*)d_ws;

  size_t off = 0;
  auto alloc = [&](size_t elems) {
    float* p = (float*)(ws + off);
    off += (elems * sizeof(float) + 255) & ~(size_t)255;
    return p;
  };
  float* r1a = alloc(2048 * 2048);
  float* r1b = alloc(2048 * 2048);
  float* r2 = alloc(1024 * 1024);
  float* r3 = alloc(512 * 512);
  float* r4 = alloc(256 * 256);
  float* r5 = alloc(128 * 128);
  float* E5 = alloc(128 * 128);
  float* E4 = alloc(256 * 256);
  float* E3 = alloc(512 * 512);
  float* E2 = alloc(1024 * 1024);
  size_t pool = off;
  const size_t VB = (size_t)4096 * 4096 * sizeof(float);
  bool big = ws_size >= pool + VB;
  float* vws = (float*)(ws + pool);

  dim3 b(64, 4);
  auto pyramid = [&](const float* r1) {
    k_restrict2<<<dim3(4, 128), b, 0, stream>>>(r1, r2, r3, 2048);
    k_restrict2<<<dim3(1, 32), b, 0, stream>>>(r3, r4, r5, 512);
    k_coarse<<<1, 1024, 0, stream>>>(r5, E5);
    k_up<<<dim3(1, 32), b, 0, stream>>>(E5, r4, E4, 256);
    k_up<<<dim3(2, 64), b, 0, stream>>>(E4, r3, E3, 512);
    k_up<<<dim3(4, 128), b, 0, stream>>>(E3, r2, E2, 1024);
  };
  dim3 fg(16, 256);

  k_smooth_restrict<<<dim3(16, 256), b, 0, stream>>>(u, r1a);
  if (big) {
    pyramid(r1a);
    k_fused<true><<<fg, 256, 0, stream>>>(u, E2, r1a, vws, r1b);
    pyramid(r1b);
    k_fused<true><<<fg, 256, 0, stream>>>(vws, E2, r1b, out, r1a);
    pyramid(r1a);
    k_fused<true><<<fg, 256, 0, stream>>>(out, E2, r1a, vws, r1b);
    pyramid(r1b);
    k_fused<false><<<fg, 256, 0, stream>>>(vws, E2, r1b, out, nullptr);
  } else {
    pyramid(r1a);
    k_fused<true><<<fg, 256, 0, stream>>>(u, E2, r1a, out, r1b);
    pyramid(r1b);
    k_fused<true><<<fg, 256, 0, stream>>>(out, E2, r1b, u, r1a);
    pyramid(r1a);
    k_fused<true><<<fg, 256, 0, stream>>>(u, E2, r1a, out, r1b);
    pyramid(r1b);
    k_fused<false><<<fg, 256, 0, stream>>>(out, E2, r1b, u, nullptr);
    hipMemcpyAsync(out, u, VB, hipMemcpyDeviceToDevice, stream);
  }
}